// Round 1
// baseline (294.093 us; speedup 1.0000x reference)
//
#include <hip/hip_runtime.h>

// Problem constants
#define BATCH 2
#define TSEQ 2048
#define DIM 1024
#define NH 16
#define HDIM 64
#define MROWS (BATCH * TSEQ)   // 4096

typedef __attribute__((ext_vector_type(4))) float f32x4;
typedef __attribute__((ext_vector_type(8))) short short8;

__device__ __forceinline__ unsigned short f2bf(float f) {
    union { float f; unsigned int u; } x; x.f = f;
    unsigned int r = x.u + 0x7fffu + ((x.u >> 16) & 1u);
    return (unsigned short)(r >> 16);
}

__device__ __forceinline__ float silu_f(float v) {
    return v / (1.f + __expf(-v));
}

__device__ __forceinline__ void gl_lds16(const void* g, void* l) {
    __builtin_amdgcn_global_load_lds(
        (const __attribute__((address_space(1))) void*)g,
        (__attribute__((address_space(3))) void*)l, 16, 0, 0);
}

// ---------------- prep: fp32 -> bf16 convert ----------------
__global__ __launch_bounds__(256) void k_convert(const float* __restrict__ in,
                                                 unsigned short* __restrict__ out,
                                                 int n4) {
    int i = blockIdx.x * 256 + threadIdx.x;
    if (i < n4) {
        float4 v = ((const float4*)in)[i];
        union { unsigned short s[4]; uint2 u; } o;
        o.s[0] = f2bf(v.x); o.s[1] = f2bf(v.y); o.s[2] = f2bf(v.z); o.s[3] = f2bf(v.w);
        ((uint2*)out)[i] = o.u;
    }
}

// ---------------- prep: transpose fp32 [R][C] -> bf16 [C][R] ----------------
__global__ __launch_bounds__(256) void k_transpose(const float* __restrict__ in,
                                                   unsigned short* __restrict__ out,
                                                   int R, int C) {
    __shared__ float tile[32][33];
    int tx = threadIdx.x, ty = threadIdx.y; // (32,8)
    int c0 = blockIdx.x * 32, r0 = blockIdx.y * 32;
    #pragma unroll
    for (int i = 0; i < 32; i += 8)
        tile[ty + i][tx] = in[(size_t)(r0 + ty + i) * C + c0 + tx];
    __syncthreads();
    #pragma unroll
    for (int i = 0; i < 32; i += 8)
        out[(size_t)(c0 + ty + i) * R + r0 + tx] = f2bf(tile[tx][ty + i]);
}

// ---------------- GEMM: C = A[M,K] @ Bt[N,K]^T, bf16 in, fp32 acc ----------------
// EPI 1: h = silu(acc + bias[n]); split cols into U(f32),V,Q,K(bf16)
// EPI 2: y = acc + bias[n] (fp32 out)
template <int EPI>
__global__ __launch_bounds__(256) void k_gemm(
    const unsigned short* __restrict__ A, const unsigned short* __restrict__ Bt,
    int M, int N, int K, const float* __restrict__ bias,
    float* __restrict__ outU, unsigned short* __restrict__ outV,
    unsigned short* __restrict__ outQ, unsigned short* __restrict__ outK,
    float* __restrict__ outY)
{
    __shared__ __align__(16) unsigned short sA[128 * 32];
    __shared__ __align__(16) unsigned short sB[128 * 32];
    const int tid = threadIdx.x;
    const int bm = blockIdx.x, bn = blockIdx.y;
    const int row0 = bm * 128, col0 = bn * 128;
    const int lane = tid & 63, w = tid >> 6;
    const int wrow = (w >> 1) * 64, wcol = (w & 1) * 64;
    const int lr = lane & 15, lk = lane >> 4;

    f32x4 acc[4][4] = {};

    for (int k0 = 0; k0 < K; k0 += 32) {
        for (int c = tid; c < 512; c += 256) {
            int r = c >> 2, kc = c & 3;
            gl_lds16(A + (size_t)(row0 + r) * K + k0 + kc * 8, sA + c * 8);
            gl_lds16(Bt + (size_t)(col0 + r) * K + k0 + kc * 8, sB + c * 8);
        }
        __syncthreads();
        short8 af[4], bf[4];
        #pragma unroll
        for (int m = 0; m < 4; ++m)
            af[m] = *(const short8*)(sA + (wrow + m * 16 + lr) * 32 + lk * 8);
        #pragma unroll
        for (int n = 0; n < 4; ++n)
            bf[n] = *(const short8*)(sB + (wcol + n * 16 + lr) * 32 + lk * 8);
        #pragma unroll
        for (int m = 0; m < 4; ++m)
            #pragma unroll
            for (int n = 0; n < 4; ++n)
                acc[m][n] = __builtin_amdgcn_mfma_f32_16x16x32_bf16(af[m], bf[n], acc[m][n], 0, 0, 0);
        __syncthreads();
    }

    #pragma unroll
    for (int m = 0; m < 4; ++m) {
        #pragma unroll
        for (int n = 0; n < 4; ++n) {
            int cg = col0 + wcol + n * 16 + lr;
            float bv = bias[cg];
            #pragma unroll
            for (int j = 0; j < 4; ++j) {
                int rg = row0 + wrow + m * 16 + lk * 4 + j;
                float v = acc[m][n][j] + bv;
                if (EPI == 1) {
                    float s = silu_f(v);
                    int sec = cg >> 10, cc = cg & 1023;
                    size_t off = ((size_t)rg << 10) + cc;
                    if (sec == 0) outU[off] = s;
                    else if (sec == 1) outV[off] = f2bf(s);
                    else if (sec == 2) outQ[off] = f2bf(s);
                    else outK[off] = f2bf(s);
                } else {
                    outY[(size_t)rg * N + cg] = v;
                }
            }
        }
    }
}

// ---------------- fused pointwise attention ----------------
// grid: 512 blocks = H(16) x qtiles(32), both batches per block.
__global__ __launch_bounds__(256) void k_attn(
    const unsigned short* __restrict__ Qb,
    const unsigned short* __restrict__ Kb,
    const unsigned short* __restrict__ Vb,
    const float* __restrict__ rab,
    float* __restrict__ AV)
{
    __shared__ __align__(16) unsigned short sQ[2][64 * 64];
    __shared__ __align__(16) unsigned short sK[2][64 * 64];
    __shared__ __align__(16) unsigned short sVt[2][64 * 64];
    __shared__ __align__(16) unsigned short sP[64 * 64];

    const int tid = threadIdx.x;
    const int lane = tid & 63;
    const int w = tid >> 6;
    const int lr = lane & 15;
    const int lk = lane >> 4;
    const int bid = blockIdx.x;
    const int h = bid & 15;
    const int qi = bid >> 4;
    const int qt = (qi < 16) ? qi : (47 - qi);  // balance causal work across CU pairs
    const int q0 = qt * 64;

    // stage Q tiles (both batches) once
    for (int bb = 0; bb < 2; ++bb)
        for (int c = tid; c < 512; c += 256) {
            int r = c >> 3, kc = c & 7;
            gl_lds16(Qb + (((size_t)(bb * TSEQ + q0 + r)) << 10) + h * 64 + kc * 8, &sQ[bb][c * 8]);
        }

    int qrow[4]; float invq[4];
    #pragma unroll
    for (int j = 0; j < 4; ++j) {
        qrow[j] = q0 + w * 16 + lk * 4 + j;
        invq[j] = 1.f / (float)(qrow[j] + 1);
    }

    f32x4 acc[2][4] = {};

    for (int kt = 0; kt <= qt; ++kt) {
        const int k0 = kt * 64;
        // stage K (both batches) via global_load_lds
        for (int bb = 0; bb < 2; ++bb)
            for (int c = tid; c < 512; c += 256) {
                int r = c >> 3, kc = c & 7;
                gl_lds16(Kb + (((size_t)(bb * TSEQ + k0 + r)) << 10) + h * 64 + kc * 8, &sK[bb][c * 8]);
            }
        // stage V transposed (reg path): sVt[d][kv]
        for (int bb = 0; bb < 2; ++bb)
            for (int c = tid; c < 512; c += 256) {
                int r = c >> 3, d0 = (c & 7) * 8;
                union { uint4 u; unsigned short s[8]; } pv;
                pv.u = *(const uint4*)(Vb + (((size_t)(bb * TSEQ + k0 + r)) << 10) + h * 64 + d0);
                #pragma unroll
                for (int i = 0; i < 8; ++i) sVt[bb][(d0 + i) * 64 + r] = pv.s[i];
            }
        __syncthreads();

        // rab is batch-independent: load tile values once into regs
        float rv[4][4];
        #pragma unroll
        for (int nt = 0; nt < 4; ++nt)
            #pragma unroll
            for (int j = 0; j < 4; ++j)
                rv[nt][j] = rab[((size_t)h * TSEQ + qrow[j]) * TSEQ + (k0 + nt * 16 + lr)];

        const bool full = (kt < qt);
        #pragma unroll
        for (int bb = 0; bb < 2; ++bb) {
            // S = Q K^T
            f32x4 s[4] = {};
            #pragma unroll
            for (int ks = 0; ks < 2; ++ks) {
                short8 aq = *(const short8*)(&sQ[bb][(w * 16 + lr) * 64 + ks * 32 + lk * 8]);
                #pragma unroll
                for (int nt = 0; nt < 4; ++nt) {
                    short8 bk = *(const short8*)(&sK[bb][(nt * 16 + lr) * 64 + ks * 32 + lk * 8]);
                    s[nt] = __builtin_amdgcn_mfma_f32_16x16x32_bf16(aq, bk, s[nt], 0, 0, 0);
                }
            }
            // P = silu(s*alpha + rab) / (q+1), causal
            #pragma unroll
            for (int nt = 0; nt < 4; ++nt) {
                int k = k0 + nt * 16 + lr;
                #pragma unroll
                for (int j = 0; j < 4; ++j) {
                    float v = s[nt][j] * 0.125f + rv[nt][j];
                    float p = (full || k <= qrow[j]) ? silu_f(v) * invq[j] : 0.f;
                    sP[(w * 16 + lk * 4 + j) * 64 + nt * 16 + lr] = f2bf(p);
                }
            }
            // AV += P @ V   (A-frag re-read from LDS in MFMA layout)
            #pragma unroll
            for (int ks = 0; ks < 2; ++ks) {
                short8 ap = *(const short8*)(&sP[(w * 16 + lr) * 64 + ks * 32 + lk * 8]);
                #pragma unroll
                for (int dt = 0; dt < 4; ++dt) {
                    short8 bv = *(const short8*)(&sVt[bb][(dt * 16 + lr) * 64 + ks * 32 + lk * 8]);
                    acc[bb][dt] = __builtin_amdgcn_mfma_f32_16x16x32_bf16(ap, bv, acc[bb][dt], 0, 0, 0);
                }
            }
        }
        __syncthreads();
    }

    #pragma unroll
    for (int bb = 0; bb < 2; ++bb)
        #pragma unroll
        for (int dt = 0; dt < 4; ++dt)
            #pragma unroll
            for (int j = 0; j < 4; ++j)
                AV[(((size_t)(bb * TSEQ + qrow[j])) << 10) + h * 64 + dt * 16 + lr] = acc[bb][dt][j];
}

// ---------------- LayerNorm(AV) * U -> z (bf16) ----------------
__global__ __launch_bounds__(256) void k_ln(const float* __restrict__ AV,
                                            const float* __restrict__ U,
                                            const float* __restrict__ lnw,
                                            const float* __restrict__ lnb,
                                            unsigned short* __restrict__ z) {
    __shared__ float red[8];
    const int row = blockIdx.x, tid = threadIdx.x;
    float4 v = ((const float4*)(AV + ((size_t)row << 10)))[tid];
    float s = v.x + v.y + v.z + v.w;
    float s2 = v.x * v.x + v.y * v.y + v.z * v.z + v.w * v.w;
    #pragma unroll
    for (int o = 32; o > 0; o >>= 1) { s += __shfl_xor(s, o); s2 += __shfl_xor(s2, o); }
    const int w = tid >> 6;
    if ((tid & 63) == 0) { red[w] = s; red[4 + w] = s2; }
    __syncthreads();
    s = red[0] + red[1] + red[2] + red[3];
    s2 = red[4] + red[5] + red[6] + red[7];
    const float mu = s * (1.f / 1024.f);
    const float var = s2 * (1.f / 1024.f) - mu * mu;
    const float rstd = rsqrtf(var + 1e-5f);
    float4 uw = ((const float4*)(U + ((size_t)row << 10)))[tid];
    float4 lw = ((const float4*)lnw)[tid];
    float4 lb = ((const float4*)lnb)[tid];
    union { unsigned short o[4]; uint2 u; } ov;
    ov.o[0] = f2bf(((v.x - mu) * rstd * lw.x + lb.x) * uw.x);
    ov.o[1] = f2bf(((v.y - mu) * rstd * lw.y + lb.y) * uw.y);
    ov.o[2] = f2bf(((v.z - mu) * rstd * lw.z + lb.z) * uw.z);
    ov.o[3] = f2bf(((v.w - mu) * rstd * lw.w + lb.w) * uw.w);
    ((uint2*)z)[((size_t)row << 8) + tid] = ov.u;
}

extern "C" void kernel_launch(void* const* d_in, const int* in_sizes, int n_in,
                              void* d_out, int out_size, void* d_ws, size_t ws_size,
                              hipStream_t stream) {
    const float* x     = (const float*)d_in[0];
    const float* rab   = (const float*)d_in[2];
    const float* W_in  = (const float*)d_in[3];
    const float* b_in  = (const float*)d_in[4];
    const float* W_out = (const float*)d_in[5];
    const float* b_out = (const float*)d_in[6];
    const float* ln_w  = (const float*)d_in[7];
    const float* ln_b  = (const float*)d_in[8];
    float* y = (float*)d_out;

    char* ws = (char*)d_ws;
    size_t off = 0;
    auto alloc = [&](size_t bytes) -> void* {
        void* p = ws + off;
        off += (bytes + 255) & ~(size_t)255;
        return p;
    };
    unsigned short* WinT  = (unsigned short*)alloc((size_t)4096 * 1024 * 2);
    unsigned short* WoutT = (unsigned short*)alloc((size_t)1024 * 1024 * 2);
    unsigned short* xb    = (unsigned short*)alloc((size_t)MROWS * DIM * 2);
    float*          Ubuf  = (float*)alloc((size_t)MROWS * DIM * 4);
    unsigned short* Vb    = (unsigned short*)alloc((size_t)MROWS * DIM * 2);
    unsigned short* Qb    = (unsigned short*)alloc((size_t)MROWS * DIM * 2);
    unsigned short* Kb    = (unsigned short*)alloc((size_t)MROWS * DIM * 2);
    float*          AV    = (float*)alloc((size_t)MROWS * DIM * 4);
    unsigned short* z     = (unsigned short*)alloc((size_t)MROWS * DIM * 2);

    // prep
    k_convert<<<dim3(4096), dim3(256), 0, stream>>>(x, xb, MROWS * DIM / 4);
    k_transpose<<<dim3(128, 32), dim3(32, 8), 0, stream>>>(W_in, WinT, 1024, 4096);
    k_transpose<<<dim3(32, 32), dim3(32, 8), 0, stream>>>(W_out, WoutT, 1024, 1024);
    // GEMM1: h = silu(x @ W_in + b_in) -> U,V,Q,K
    k_gemm<1><<<dim3(32, 32), dim3(256), 0, stream>>>(xb, WinT, MROWS, 4096, 1024,
                                                      b_in, Ubuf, Vb, Qb, Kb, nullptr);
    // attention
    k_attn<<<dim3(512), dim3(256), 0, stream>>>(Qb, Kb, Vb, rab, AV);
    // LN * U
    k_ln<<<dim3(MROWS), dim3(256), 0, stream>>>(AV, Ubuf, ln_w, ln_b, z);
    // GEMM2: y = z @ W_out + b_out
    k_gemm<2><<<dim3(32, 8), dim3(256), 0, stream>>>(z, WoutT, MROWS, 1024, 1024,
                                                     b_out, nullptr, nullptr, nullptr, nullptr, y);
}

// Round 2
// 216.286 us; speedup vs baseline: 1.3597x; 1.3597x over previous
//
#include <hip/hip_runtime.h>

// Problem constants
#define BATCH 2
#define TSEQ 2048
#define DIM 1024
#define NH 16
#define HDIM 64
#define MROWS (BATCH * TSEQ)   // 4096

typedef __attribute__((ext_vector_type(4))) float f32x4;
typedef __attribute__((ext_vector_type(8))) short short8;

__device__ __forceinline__ unsigned short f2bf(float f) {
    union { float f; unsigned int u; } x; x.f = f;
    unsigned int r = x.u + 0x7fffu + ((x.u >> 16) & 1u);
    return (unsigned short)(r >> 16);
}

__device__ __forceinline__ float silu_f(float v) {
    return v / (1.f + __expf(-v));
}

__device__ __forceinline__ void gl_lds16(const void* g, void* l) {
    __builtin_amdgcn_global_load_lds(
        (const __attribute__((address_space(1))) void*)g,
        (__attribute__((address_space(3))) void*)l, 16, 0, 0);
}

// swizzled LDS 16B-chunk read: row stride 128B, chunk index XOR (row&7)
__device__ __forceinline__ short8 rd_swz(const unsigned short* base, int row, int chunk) {
    const char* b = (const char*)base;
    return *(const short8*)(b + row * 128 + (((chunk ^ (row & 7)) << 4)));
}

// ---------------- prep: fp32 -> bf16 convert ----------------
__global__ __launch_bounds__(256) void k_convert(const float* __restrict__ in,
                                                 unsigned short* __restrict__ out,
                                                 int n4) {
    int i = blockIdx.x * 256 + threadIdx.x;
    if (i < n4) {
        float4 v = ((const float4*)in)[i];
        union { unsigned short s[4]; uint2 u; } o;
        o.s[0] = f2bf(v.x); o.s[1] = f2bf(v.y); o.s[2] = f2bf(v.z); o.s[3] = f2bf(v.w);
        ((uint2*)out)[i] = o.u;
    }
}

// ---------------- prep: transpose fp32 [R][C] -> bf16 [C][R] ----------------
__global__ __launch_bounds__(256) void k_transpose(const float* __restrict__ in,
                                                   unsigned short* __restrict__ out,
                                                   int R, int C) {
    __shared__ float tile[32][33];
    int tx = threadIdx.x, ty = threadIdx.y; // (32,8)
    int c0 = blockIdx.x * 32, r0 = blockIdx.y * 32;
    #pragma unroll
    for (int i = 0; i < 32; i += 8)
        tile[ty + i][tx] = in[(size_t)(r0 + ty + i) * C + c0 + tx];
    __syncthreads();
    #pragma unroll
    for (int i = 0; i < 32; i += 8)
        out[(size_t)(c0 + ty + i) * R + r0 + tx] = f2bf(tile[tx][ty + i]);
}

// ---------------- prep: transpose bf16 [R][C] -> bf16 [C][R] ----------------
__global__ __launch_bounds__(256) void k_transpose_bf16(const unsigned short* __restrict__ in,
                                                        unsigned short* __restrict__ out,
                                                        int R, int C) {
    __shared__ unsigned short t[64][66];
    int tx = threadIdx.x, ty = threadIdx.y; // (64,4)
    int c0 = blockIdx.x * 64, r0 = blockIdx.y * 64;
    #pragma unroll
    for (int i = 0; i < 64; i += 4)
        t[ty + i][tx] = in[(size_t)(r0 + ty + i) * C + c0 + tx];
    __syncthreads();
    #pragma unroll
    for (int i = 0; i < 64; i += 4)
        out[(size_t)(c0 + ty + i) * R + r0 + tx] = t[tx][ty + i];
}

// ---------------- GEMM: C = A[M,K] @ Bt[N,K]^T, bf16 in, fp32 acc ----------------
template <int EPI>
__global__ __launch_bounds__(256) void k_gemm(
    const unsigned short* __restrict__ A, const unsigned short* __restrict__ Bt,
    int M, int N, int K, const float* __restrict__ bias,
    float* __restrict__ outU, unsigned short* __restrict__ outV,
    unsigned short* __restrict__ outQ, unsigned short* __restrict__ outK,
    float* __restrict__ outY)
{
    __shared__ __align__(16) unsigned short sA[128 * 32];
    __shared__ __align__(16) unsigned short sB[128 * 32];
    const int tid = threadIdx.x;
    const int bm = blockIdx.x, bn = blockIdx.y;
    const int row0 = bm * 128, col0 = bn * 128;
    const int lane = tid & 63, w = tid >> 6;
    const int wrow = (w >> 1) * 64, wcol = (w & 1) * 64;
    const int lr = lane & 15, lk = lane >> 4;

    f32x4 acc[4][4] = {};

    for (int k0 = 0; k0 < K; k0 += 32) {
        for (int c = tid; c < 512; c += 256) {
            int r = c >> 2, kc = c & 3;
            gl_lds16(A + (size_t)(row0 + r) * K + k0 + kc * 8, sA + c * 8);
            gl_lds16(Bt + (size_t)(col0 + r) * K + k0 + kc * 8, sB + c * 8);
        }
        __syncthreads();
        short8 af[4], bf[4];
        #pragma unroll
        for (int m = 0; m < 4; ++m)
            af[m] = *(const short8*)(sA + (wrow + m * 16 + lr) * 32 + lk * 8);
        #pragma unroll
        for (int n = 0; n < 4; ++n)
            bf[n] = *(const short8*)(sB + (wcol + n * 16 + lr) * 32 + lk * 8);
        #pragma unroll
        for (int m = 0; m < 4; ++m)
            #pragma unroll
            for (int n = 0; n < 4; ++n)
                acc[m][n] = __builtin_amdgcn_mfma_f32_16x16x32_bf16(af[m], bf[n], acc[m][n], 0, 0, 0);
        __syncthreads();
    }

    #pragma unroll
    for (int m = 0; m < 4; ++m) {
        #pragma unroll
        for (int n = 0; n < 4; ++n) {
            int cg = col0 + wcol + n * 16 + lr;
            float bv = bias[cg];
            #pragma unroll
            for (int j = 0; j < 4; ++j) {
                int rg = row0 + wrow + m * 16 + lk * 4 + j;
                float v = acc[m][n][j] + bv;
                if (EPI == 1) {
                    float s = silu_f(v);
                    int sec = cg >> 10, cc = cg & 1023;
                    size_t off = ((size_t)rg << 10) + cc;
                    if (sec == 0) outU[off] = s;
                    else if (sec == 1) outV[off] = f2bf(s);
                    else if (sec == 2) outQ[off] = f2bf(s);
                    else outK[off] = f2bf(s);
                } else {
                    outY[(size_t)rg * N + cg] = v;
                }
            }
        }
    }
}

// ---------------- fused pointwise attention ----------------
// grid: 1024 blocks = 4 groups x 16 qtile-slots x 16 heads; one batch per block.
// Balanced: under round-robin dispatch each CU's 4 blocks sum to 66 kv-iters.
__global__ __launch_bounds__(256) void k_attn(
    const unsigned short* __restrict__ Qb,
    const unsigned short* __restrict__ Kb,
    const unsigned short* __restrict__ Vt,   // [1024][4096] = V transposed
    const float* __restrict__ rab,
    float* __restrict__ AV)
{
    __shared__ __align__(16) unsigned short sK[2][64 * 64];
    __shared__ __align__(16) unsigned short sVt[2][64 * 64];
    __shared__ __align__(16) unsigned short sP[64 * 64];

    const int tid = threadIdx.x;
    const int lane = tid & 63;
    const int w = tid >> 6;
    const int lr = lane & 15;
    const int lk = lane >> 4;

    const int bid = blockIdx.x;
    const int idx = bid & 255;
    const int g = bid >> 8;
    const int h = idx & 15;
    const int r_ = idx >> 4;
    const int bb = g >> 1;
    const int qt = (g & 1) ? (31 - r_) : r_;
    const int q0 = qt * 64;

    // Q fragment in registers (wave-private rows q0 + w*16 + lr)
    short8 qreg[2];
    #pragma unroll
    for (int ks = 0; ks < 2; ++ks)
        qreg[ks] = *(const short8*)(Qb + (((size_t)(bb * TSEQ + q0 + w * 16 + lr)) << 10)
                                     + h * 64 + ks * 32 + lk * 8);

    int qrow[4]; float invq[4];
    #pragma unroll
    for (int j = 0; j < 4; ++j) {
        qrow[j] = q0 + w * 16 + lk * 4 + j;
        invq[j] = 1.f / (float)(qrow[j] + 1);
    }

    f32x4 acc[4] = {};

    // staging: K tile rows = key pos, cols = head dim (swizzled chunks);
    //          Vt tile rows = head dim, cols = key pos (swizzled chunks)
    #define STAGE(buf, kt_) do {                                                     \
        int k0s = (kt_) * 64;                                                        \
        for (int c = tid; c < 512; c += 256) {                                       \
            int rr = c >> 3, kc = c & 7;                                             \
            int kcs = kc ^ (rr & 7);                                                 \
            gl_lds16(Kb + (((size_t)(bb * TSEQ + k0s + rr)) << 10) + h * 64 + kcs * 8,\
                     sK[buf] + c * 8);                                               \
            gl_lds16(Vt + (((size_t)(h * 64 + rr)) << 12) + bb * TSEQ + k0s + kcs * 8,\
                     sVt[buf] + c * 8);                                              \
        }                                                                            \
    } while (0)

    STAGE(0, 0);
    __syncthreads();

    int cur = 0;
    for (int kt = 0; kt <= qt; ++kt) {
        const int k0 = kt * 64;
        if (kt < qt) STAGE(cur ^ 1, kt + 1);

        // rab tile values (f32) for this q-strip
        float rv[4][4];
        #pragma unroll
        for (int nt = 0; nt < 4; ++nt)
            #pragma unroll
            for (int j = 0; j < 4; ++j)
                rv[nt][j] = rab[((size_t)h * TSEQ + qrow[j]) * TSEQ + k0 + nt * 16 + lr];

        // S = Q K^T
        f32x4 s[4] = {};
        #pragma unroll
        for (int ks = 0; ks < 2; ++ks) {
            #pragma unroll
            for (int nt = 0; nt < 4; ++nt)
                s[nt] = __builtin_amdgcn_mfma_f32_16x16x32_bf16(
                    qreg[ks], rd_swz(sK[cur], nt * 16 + lr, ks * 4 + lk), s[nt], 0, 0, 0);
        }

        // P = silu(s*alpha + rab) / (q+1), causal; store to wave-private sP strip
        const bool full = (kt < qt);
        char* pb = (char*)sP;
        #pragma unroll
        for (int nt = 0; nt < 4; ++nt) {
            int k = k0 + nt * 16 + lr;
            #pragma unroll
            for (int j = 0; j < 4; ++j) {
                int prow = w * 16 + lk * 4 + j;
                float v = s[nt][j] * 0.125f + rv[nt][j];
                float p = (full || k <= qrow[j]) ? silu_f(v) * invq[j] : 0.f;
                *(unsigned short*)(pb + prow * 128 + (((nt * 16 + lr) * 2) ^ ((prow & 7) << 4)))
                    = f2bf(p);
            }
        }

        // AV += P @ V
        #pragma unroll
        for (int ks = 0; ks < 2; ++ks) {
            short8 ap = rd_swz(sP, w * 16 + lr, ks * 4 + lk);
            #pragma unroll
            for (int dt = 0; dt < 4; ++dt)
                acc[dt] = __builtin_amdgcn_mfma_f32_16x16x32_bf16(
                    ap, rd_swz(sVt[cur], dt * 16 + lr, ks * 4 + lk), acc[dt], 0, 0, 0);
        }

        __syncthreads();
        cur ^= 1;
    }
    #undef STAGE

    #pragma unroll
    for (int dt = 0; dt < 4; ++dt)
        #pragma unroll
        for (int j = 0; j < 4; ++j)
            AV[(((size_t)(bb * TSEQ + qrow[j])) << 10) + h * 64 + dt * 16 + lr] = acc[dt][j];
}

// ---------------- LayerNorm(AV) * U -> z (bf16) ----------------
__global__ __launch_bounds__(256) void k_ln(const float* __restrict__ AV,
                                            const float* __restrict__ U,
                                            const float* __restrict__ lnw,
                                            const float* __restrict__ lnb,
                                            unsigned short* __restrict__ z) {
    __shared__ float red[8];
    const int row = blockIdx.x, tid = threadIdx.x;
    float4 v = ((const float4*)(AV + ((size_t)row << 10)))[tid];
    float s = v.x + v.y + v.z + v.w;
    float s2 = v.x * v.x + v.y * v.y + v.z * v.z + v.w * v.w;
    #pragma unroll
    for (int o = 32; o > 0; o >>= 1) { s += __shfl_xor(s, o); s2 += __shfl_xor(s2, o); }
    const int w = tid >> 6;
    if ((tid & 63) == 0) { red[w] = s; red[4 + w] = s2; }
    __syncthreads();
    s = red[0] + red[1] + red[2] + red[3];
    s2 = red[4] + red[5] + red[6] + red[7];
    const float mu = s * (1.f / 1024.f);
    const float var = s2 * (1.f / 1024.f) - mu * mu;
    const float rstd = rsqrtf(var + 1e-5f);
    float4 uw = ((const float4*)(U + ((size_t)row << 10)))[tid];
    float4 lw = ((const float4*)lnw)[tid];
    float4 lb = ((const float4*)lnb)[tid];
    union { unsigned short o[4]; uint2 u; } ov;
    ov.o[0] = f2bf(((v.x - mu) * rstd * lw.x + lb.x) * uw.x);
    ov.o[1] = f2bf(((v.y - mu) * rstd * lw.y + lb.y) * uw.y);
    ov.o[2] = f2bf(((v.z - mu) * rstd * lw.z + lb.z) * uw.z);
    ov.o[3] = f2bf(((v.w - mu) * rstd * lw.w + lb.w) * uw.w);
    ((uint2*)z)[((size_t)row << 8) + tid] = ov.u;
}

extern "C" void kernel_launch(void* const* d_in, const int* in_sizes, int n_in,
                              void* d_out, int out_size, void* d_ws, size_t ws_size,
                              hipStream_t stream) {
    const float* x     = (const float*)d_in[0];
    const float* rab   = (const float*)d_in[2];
    const float* W_in  = (const float*)d_in[3];
    const float* b_in  = (const float*)d_in[4];
    const float* W_out = (const float*)d_in[5];
    const float* b_out = (const float*)d_in[6];
    const float* ln_w  = (const float*)d_in[7];
    const float* ln_b  = (const float*)d_in[8];
    float* y = (float*)d_out;

    char* ws = (char*)d_ws;
    size_t off = 0;
    auto alloc = [&](size_t bytes) -> void* {
        void* p = ws + off;
        off += (bytes + 255) & ~(size_t)255;
        return p;
    };
    unsigned short* WinT  = (unsigned short*)alloc((size_t)4096 * 1024 * 2);
    unsigned short* WoutT = (unsigned short*)alloc((size_t)1024 * 1024 * 2);
    unsigned short* xb    = (unsigned short*)alloc((size_t)MROWS * DIM * 2);
    float*          Ubuf  = (float*)alloc((size_t)MROWS * DIM * 4);
    unsigned short* Vb    = (unsigned short*)alloc((size_t)MROWS * DIM * 2);
    unsigned short* Qb    = (unsigned short*)alloc((size_t)MROWS * DIM * 2);
    unsigned short* Kb    = (unsigned short*)alloc((size_t)MROWS * DIM * 2);
    unsigned short* Vtb   = (unsigned short*)alloc((size_t)DIM * MROWS * 2);
    float*          AV    = (float*)alloc((size_t)MROWS * DIM * 4);
    unsigned short* z     = (unsigned short*)alloc((size_t)MROWS * DIM * 2);

    // prep
    k_convert<<<dim3(4096), dim3(256), 0, stream>>>(x, xb, MROWS * DIM / 4);
    k_transpose<<<dim3(128, 32), dim3(32, 8), 0, stream>>>(W_in, WinT, 1024, 4096);
    k_transpose<<<dim3(32, 32), dim3(32, 8), 0, stream>>>(W_out, WoutT, 1024, 1024);
    // GEMM1: h = silu(x @ W_in + b_in) -> U,V,Q,K
    k_gemm<1><<<dim3(32, 32), dim3(256), 0, stream>>>(xb, WinT, MROWS, 4096, 1024,
                                                      b_in, Ubuf, Vb, Qb, Kb, nullptr);
    // V -> V^T (global), so attention can stage both K and V^T via global_load_lds
    k_transpose_bf16<<<dim3(16, 64), dim3(64, 4), 0, stream>>>(Vb, Vtb, MROWS, DIM);
    // attention
    k_attn<<<dim3(1024), dim3(256), 0, stream>>>(Qb, Kb, Vtb, rab, AV);
    // LN * U
    k_ln<<<dim3(MROWS), dim3(256), 0, stream>>>(AV, Ubuf, ln_w, ln_b, z);
    // GEMM2: y = z @ W_out + b_out
    k_gemm<2><<<dim3(32, 8), dim3(256), 0, stream>>>(z, WoutT, MROWS, 1024, 1024,
                                                     b_out, nullptr, nullptr, nullptr, nullptr, y);
}